// Round 4
// baseline (830.647 us; speedup 1.0000x reference)
//
#include <hip/hip_runtime.h>
#include <hip/hip_bf16.h>

// ---------------------------------------------------------------------------
// BlipAttention: x(32,1024,768) -> qkv -> attention -> scramble -> proj
// All-bf16 MFMA pipeline, fp32 accumulation.
// R2: softmax fused into G2/G4 epilogues (exp + atomic row sums + 1/Z scale).
// R3: 32x32x16 MFMA (2382 TF ceiling), wave = 64x64 out = 2x2 tiles.
// R4: operand-order LDS layout — global_load_lds lane gather IS the fragment
//     permutation; ds_read_b128 at base+lane*16 (linear, 0 bank conflicts).
// ---------------------------------------------------------------------------

#define TM 128
#define TN 128
#define BK 64

typedef __attribute__((ext_vector_type(8))) short bf16x8;
typedef __attribute__((ext_vector_type(16))) float f32x16;

__device__ __forceinline__ unsigned short f2b(float f) {
  unsigned int u = __float_as_uint(f);
  u = u + 0x7fffu + ((u >> 16) & 1u);
  return (unsigned short)(u >> 16);
}

__device__ __forceinline__ void g2l16(const void* g, void* l) {
  __builtin_amdgcn_global_load_lds(
      (const __attribute__((address_space(1))) unsigned int*)g,
      (__attribute__((address_space(3))) unsigned int*)l, 16, 0, 0);
}

// NT GEMM: C[m][n] = sum_k A[m][k] * B[n][k]; A,B bf16 row-major (K contig).
// EPI 1: QKV split: bias add, write Q/K/V bf16 (seg = blockIdx.x/6)
// EPI 2: fp32 out + bias
// EPI 3: E = exp(v*scale) bf16 out + atomic row-sum accumulation into Z
// EPI 4: bf16 out = v * (1/Z[col])
//
// LDS layout (operand order): 16B chunk index = (g<<8)|(s<<6)|lane where
// g = 32-row group (0..3), s = K-slice (0..3), lane = (hi<<5)|m.
// Chunk holds A[row = g*32 + m][k = s*16 + hi*8 .. +8).
// Fragment read for (t,s) by wave w: g = ((w&1)<<1)|t (A) / ((w>>1)<<1)|t (B),
// address = (g<<11) + (s<<9) + lane*8 ushorts -> linear in lane.
template <int EPI>
__global__ __launch_bounds__(256) void gemm_nt(
    const unsigned short* __restrict__ A, const unsigned short* __restrict__ B,
    unsigned short* __restrict__ Cb, unsigned short* __restrict__ Ck,
    unsigned short* __restrict__ Cv, float* __restrict__ Cf,
    const float* __restrict__ bias, float* __restrict__ Z, int K, int lda,
    int ldb, int ldc, long bsA, long bsB, long bsC, float scale) {
  __shared__ unsigned short As[TM * BK];  // 16 KB
  __shared__ unsigned short Bs[TN * BK];  // 16 KB

  const int bz = blockIdx.z;
  const unsigned short* Ag = A + (long)bz * bsA + (long)(blockIdx.y * TM) * lda;
  const unsigned short* Bg = B + (long)bz * bsB + (long)(blockIdx.x * TN) * ldb;

  const int tid = threadIdx.x;
  const int wave = tid >> 6;
  const int lane = tid & 63;
  const int l31 = lane & 31;
  const int hi = lane >> 5;
  const int wm = (wave & 1) << 6;
  const int wn = (wave >> 1) << 6;

  f32x16 acc[2][2];
#pragma unroll
  for (int mt = 0; mt < 2; ++mt)
#pragma unroll
    for (int nt = 0; nt < 2; ++nt)
#pragma unroll
      for (int p = 0; p < 16; ++p) acc[mt][nt][p] = 0.f;

  // staging: wave w loads rows [w*32, w*32+32); issue s covers k-slice
  // [s*16, s*16+16); lane (hi,l31) -> row w*32+l31, k byte-chunk hi.
  const unsigned short* Agw = Ag + (long)((wave << 5) + l31) * lda + (hi << 3);
  const unsigned short* Bgw = Bg + (long)((wave << 5) + l31) * ldb + (hi << 3);

  for (int k0 = 0; k0 < K; k0 += BK) {
#pragma unroll
    for (int s = 0; s < 4; ++s) {
      g2l16(Agw + k0 + (s << 4), &As[(wave << 11) + (s << 9)]);
      g2l16(Bgw + k0 + (s << 4), &Bs[(wave << 11) + (s << 9)]);
    }
    __syncthreads();
#pragma unroll
    for (int s = 0; s < 4; ++s) {
      bf16x8 af[2], bfr[2];
#pragma unroll
      for (int t = 0; t < 2; ++t) {
        const int ga = (((wave & 1) << 1) | t);
        const int gb = (((wave >> 1) << 1) | t);
        af[t] = *(const bf16x8*)&As[(ga << 11) + (s << 9) + (lane << 3)];
        bfr[t] = *(const bf16x8*)&Bs[(gb << 11) + (s << 9) + (lane << 3)];
      }
#pragma unroll
      for (int mt = 0; mt < 2; ++mt)
#pragma unroll
        for (int nt = 0; nt < 2; ++nt)
          acc[mt][nt] = __builtin_amdgcn_mfma_f32_32x32x16_bf16(
              af[mt], bfr[nt], acc[mt][nt], 0, 0, 0);
    }
    __syncthreads();
  }

  // C/D layout (m74/m101): col = lane&31, row = (p&3) + 8*(p>>2) + 4*hi
  const int row0 = blockIdx.y * TM + wm + 4 * hi;
  const int col0 = blockIdx.x * TN + wn;
  float esum[2][16];  // EPI 3 only: per (mt, p) row sums across both nt
#pragma unroll
  for (int mt = 0; mt < 2; ++mt) {
#pragma unroll
    for (int nt = 0; nt < 2; ++nt) {
      const int col = col0 + nt * 32 + l31;
      float bv = 0.f;
      if constexpr (EPI == 1 || EPI == 2) bv = bias[col];
      float zinv = 1.f;
      if constexpr (EPI == 4) zinv = 1.f / Z[(long)bz * 1024 + col];
#pragma unroll
      for (int p = 0; p < 16; ++p) {
        const float v = acc[mt][nt][p];
        const long rr = row0 + mt * 32 + (p & 3) + ((p >> 2) << 3);
        if constexpr (EPI == 1) {
          const int seg = blockIdx.x / 6;  // 0:Q 1:K 2:V (TN=128 divides 768)
          const int cl = col - seg * 768;
          unsigned short* O = (seg == 0) ? Cb : ((seg == 1) ? Ck : Cv);
          O[rr * 768 + cl] = f2b(v + bv);
        } else if constexpr (EPI == 2) {
          Cf[rr * ldc + col] = v + bv;
        } else if constexpr (EPI == 3) {
          const float e = __expf(v * scale);
          if (nt == 0)
            esum[mt][p] = e;
          else
            esum[mt][p] += e;
          unsigned short* C = Cb + (long)bz * bsC;
          C[rr * ldc + col] = f2b(e);
        } else {  // EPI 4
          unsigned short* C = Cb + (long)bz * bsC;
          C[rr * ldc + col] = f2b(v * zinv);
        }
      }
    }
    if constexpr (EPI == 3) {
#pragma unroll
      for (int p = 0; p < 16; ++p) {
        float s = esum[mt][p];
        s += __shfl_xor(s, 1);
        s += __shfl_xor(s, 2);
        s += __shfl_xor(s, 4);
        s += __shfl_xor(s, 8);
        s += __shfl_xor(s, 16);
        if (l31 == 0) {
          const long rr = row0 + mt * 32 + (p & 3) + ((p >> 2) << 3);
          atomicAdd(&Z[(long)bz * 1024 + rr], s);
        }
      }
    }
  }
}

// fp32 -> bf16 elementwise (x), vectorized
__global__ __launch_bounds__(256) void cvt_x(const float4* __restrict__ x,
                                             ushort4* __restrict__ y, long n4) {
  const long i = (long)blockIdx.x * 256 + threadIdx.x;
  if (i < n4) {
    float4 f = x[i];
    ushort4 o;
    o.x = f2b(f.x); o.y = f2b(f.y); o.z = f2b(f.z); o.w = f2b(f.w);
    y[i] = o;
  }
}

// W[RxC] fp32 -> Wt[CxR] bf16 (coalesced writes; small tensors)
__global__ __launch_bounds__(256) void tcvt(const float* __restrict__ W,
                                            unsigned short* __restrict__ Wt,
                                            int R, int C) {
  const long i = (long)blockIdx.x * 256 + threadIdx.x;
  if (i < (long)R * C) {
    const int k = (int)(i % R);
    const int j = (int)(i / R);
    Wt[i] = f2b(W[(long)k * C + j]);
  }
}

// per-batch V[1024][768] -> Vt[768][1024], bf16, 64x64 LDS tiles
__global__ __launch_bounds__(256) void transpose_v(
    const unsigned short* __restrict__ V, unsigned short* __restrict__ Vt) {
  __shared__ unsigned short T[64][72];
  const int b = blockIdx.z;
  const int d0 = blockIdx.x << 6;
  const int m0 = blockIdx.y << 6;
  const unsigned short* Vb = V + (long)b * 786432;
  unsigned short* Vtb = Vt + (long)b * 786432;
  const int tid = threadIdx.x;
  const int r = tid >> 2;
  const int c4 = tid & 3;
#pragma unroll
  for (int h = 0; h < 2; ++h) {
    const int cc = (c4 + (h << 2)) << 3;
    *(uint4*)&T[r][cc] = *(const uint4*)&Vb[(long)(m0 + r) * 768 + d0 + cc];
  }
  __syncthreads();
#pragma unroll
  for (int h = 0; h < 2; ++h) {
    const int mm = (c4 + (h << 2)) << 3;
    alignas(16) unsigned short tmp[8];
#pragma unroll
    for (int e = 0; e < 8; ++e) tmp[e] = T[mm + e][r];
    *(uint4*)&Vtb[(long)(d0 + r) * 1024 + m0 + mm] = *(uint4*)tmp;
  }
}

extern "C" void kernel_launch(void* const* d_in, const int* in_sizes, int n_in,
                              void* d_out, int out_size, void* d_ws,
                              size_t ws_size, hipStream_t stream) {
  const float* x = (const float*)d_in[0];
  const float* qkv_w = (const float*)d_in[1];
  const float* qkv_b = (const float*)d_in[2];
  const float* proj_w = (const float*)d_in[3];
  const float* proj_b = (const float*)d_in[4];
  float* out = (float*)d_out;

  char* ws = (char*)d_ws;
  unsigned short* x_bf = (unsigned short*)ws;
  unsigned short* Wqkv = (unsigned short*)(ws + 50331648);
  unsigned short* Wp = (unsigned short*)(ws + 53870592);
  unsigned short* Qb = (unsigned short*)(ws + 55050240);
  unsigned short* Kb = (unsigned short*)(ws + 105381888);
  unsigned short* Vb = (unsigned short*)(ws + 155713536);
  unsigned short* Sb = (unsigned short*)(ws + 206045184);
  unsigned short* Vt = x_bf;  // x_bf dead after G1
  unsigned short* Hb = Qb;    // Q dead after G2
  float* Zs = (float*)Vb;     // V dead after transpose_v

  // 1) convert inputs to bf16 (weights also transposed to [n][k])
  cvt_x<<<24576, 256, 0, stream>>>((const float4*)x, (ushort4*)x_bf, 6291456);
  tcvt<<<(1769472 + 255) / 256, 256, 0, stream>>>(qkv_w, Wqkv, 768, 2304);
  tcvt<<<(589824 + 255) / 256, 256, 0, stream>>>(proj_w, Wp, 768, 768);

  // 2) QKV GEMM: [32768x768] x [2304x768]^T + bias -> Q,K,V bf16
  gemm_nt<1><<<dim3(18, 256, 1), 256, 0, stream>>>(
      x_bf, Wqkv, Qb, Kb, Vb, nullptr, qkv_b, nullptr, 768, 768, 768, 0, 0, 0,
      0, 1.f);

  // 3) V -> V^T per batch
  transpose_v<<<dim3(12, 16, 32), 256, 0, stream>>>(Vb, Vt);

  // 3b) zero the softmax row-sum accumulator (V region is now dead)
  hipMemsetAsync(Zs, 0, 32 * 1024 * sizeof(float), stream);

  // 4) E[b] = exp(Q[b] K[b]^T / sqrt(768)) bf16 + row sums into Zs
  gemm_nt<3><<<dim3(8, 8, 32), 256, 0, stream>>>(
      Qb, Kb, Sb, nullptr, nullptr, nullptr, nullptr, Zs, 768, 768, 768, 1024,
      786432, 786432, 1048576, 0.03608439182435161f);

  // 5) O^T: hbuf[b][d][n] = (sum_m Vt[b][d][m] E[b][n][m]) / Z[b][n]
  gemm_nt<4><<<dim3(8, 6, 32), 256, 0, stream>>>(
      Vt, Sb, Hb, nullptr, nullptr, nullptr, nullptr, Zs, 1024, 1024, 1024,
      1024, 786432, 1048576, 786432, 1.f);

  // 6) proj: out[32768x768] = hbuf x Wp^T + bias, fp32
  gemm_nt<2><<<dim3(6, 256, 1), 256, 0, stream>>>(
      Hb, Wp, nullptr, nullptr, nullptr, out, proj_b, nullptr, 768, 768, 768,
      768, 0, 0, 0, 1.f);
}

// Round 5
// 613.232 us; speedup vs baseline: 1.3545x; 1.3545x over previous
//
#include <hip/hip_runtime.h>
#include <hip/hip_bf16.h>

// ---------------------------------------------------------------------------
// BlipAttention: x(32,1024,768) -> qkv -> attention -> scramble -> proj
// All-bf16 MFMA pipeline, fp32 accumulation.
// R2: softmax fused into G2/G4 epilogues (exp + atomic row sums + 1/Z scale).
// R3: 32x32x16 MFMA (2382 TF ceiling), wave = 64x64 out = 2x2 tiles.
// R4 (reverted): operand-order LDS killed staging coalescing (64 scattered
//     16B reqs/instr) — HBM 2481->1624 GB/s. Staging must stay row-segment.
// R5: generalized XOR swizzle sigma(r,c) = c ^ (r&7) ^ (((r>>3)&3)<<1):
//     slot now depends on lane bits l3/l4 too -> 2-way max in 8-lane strided
//     phases (free) while keeping 128B-coalesced staging.
// ---------------------------------------------------------------------------

#define TM 128
#define TN 128
#define BK 64

typedef __attribute__((ext_vector_type(8))) short bf16x8;
typedef __attribute__((ext_vector_type(16))) float f32x16;

__device__ __forceinline__ unsigned short f2b(float f) {
  unsigned int u = __float_as_uint(f);
  u = u + 0x7fffu + ((u >> 16) & 1u);
  return (unsigned short)(u >> 16);
}

__device__ __forceinline__ void g2l16(const void* g, void* l) {
  __builtin_amdgcn_global_load_lds(
      (const __attribute__((address_space(1))) unsigned int*)g,
      (__attribute__((address_space(3))) unsigned int*)l, 16, 0, 0);
}

// NT GEMM: C[m][n] = sum_k A[m][k] * B[n][k]; A,B bf16 row-major (K contig).
// EPI 1: QKV split: bias add, write Q/K/V bf16 (seg = blockIdx.x/6)
// EPI 2: fp32 out + bias
// EPI 3: E = exp(v*scale) bf16 out + atomic row-sum accumulation into Z
// EPI 4: bf16 out = v * (1/Z[col])
//
// LDS: row r = 64 ushorts (8 chunks of 16B); chunk c of row r lives at slot
// sigma = c ^ g(r), g(r) = (r&7) ^ (((r>>3)&3)<<1). Staging lane (row group)
// reads global chunk sj ^ g(r) into LDS slot sj -> permutation within the
// row's 128B segment (coalescing preserved).
template <int EPI>
__global__ __launch_bounds__(256) void gemm_nt(
    const unsigned short* __restrict__ A, const unsigned short* __restrict__ B,
    unsigned short* __restrict__ Cb, unsigned short* __restrict__ Ck,
    unsigned short* __restrict__ Cv, float* __restrict__ Cf,
    const float* __restrict__ bias, float* __restrict__ Z, int K, int lda,
    int ldb, int ldc, long bsA, long bsB, long bsC, float scale) {
  __shared__ unsigned short As[TM * BK];  // 16 KB
  __shared__ unsigned short Bs[TN * BK];  // 16 KB

  const int bz = blockIdx.z;
  const unsigned short* Ag = A + (long)bz * bsA + (long)(blockIdx.y * TM) * lda;
  const unsigned short* Bg = B + (long)bz * bsB + (long)(blockIdx.x * TN) * ldb;

  const int tid = threadIdx.x;
  const int wave = tid >> 6;
  const int lane = tid & 63;
  const int l31 = lane & 31;
  const int hi = lane >> 5;
  const int wm = (wave & 1) << 6;
  const int wn = (wave >> 1) << 6;

  f32x16 acc[2][2];
#pragma unroll
  for (int mt = 0; mt < 2; ++mt)
#pragma unroll
    for (int nt = 0; nt < 2; ++nt)
#pragma unroll
      for (int p = 0; p < 16; ++p) acc[mt][nt][p] = 0.f;

  // staging: wave covers rows wave*32..+31; 4 issues of 8 rows; lane ->
  // (row = i*8 + lane>>3, LDS slot sj = lane&7, global chunk sj ^ g(r)).
  const int sj = lane & 7;
  const int srow = lane >> 3;

  // fragment-read swizzle bases (hoisted): g(ra) per tile t
  int ga[2], gb[2];
#pragma unroll
  for (int t = 0; t < 2; ++t) {
    const int ra = wm + t * 32 + l31;
    const int rb = wn + t * 32 + l31;
    ga[t] = (ra & 7) ^ (((ra >> 3) & 3) << 1);
    gb[t] = (rb & 7) ^ (((rb >> 3) & 3) << 1);
  }

  for (int k0 = 0; k0 < K; k0 += BK) {
#pragma unroll
    for (int i = 0; i < 4; ++i) {
      const int r = (wave << 5) + (i << 3) + srow;
      const int g = srow ^ ((i & 3) << 1);  // (r&7) ^ (((r>>3)&3)<<1)
      const int cg = (sj ^ g) << 3;
      g2l16(Ag + (long)r * lda + (k0 + cg), &As[(wave << 11) + (i << 9)]);
      g2l16(Bg + (long)r * ldb + (k0 + cg), &Bs[(wave << 11) + (i << 9)]);
    }
    __syncthreads();
#pragma unroll
    for (int s = 0; s < 4; ++s) {
      const int c = (s << 1) | hi;
      bf16x8 af[2], bfr[2];
#pragma unroll
      for (int t = 0; t < 2; ++t) {
        const int ra = wm + t * 32 + l31;
        const int rb = wn + t * 32 + l31;
        af[t] = *(const bf16x8*)&As[(ra << 6) + ((c ^ ga[t]) << 3)];
        bfr[t] = *(const bf16x8*)&Bs[(rb << 6) + ((c ^ gb[t]) << 3)];
      }
#pragma unroll
      for (int mt = 0; mt < 2; ++mt)
#pragma unroll
        for (int nt = 0; nt < 2; ++nt)
          acc[mt][nt] = __builtin_amdgcn_mfma_f32_32x32x16_bf16(
              af[mt], bfr[nt], acc[mt][nt], 0, 0, 0);
    }
    __syncthreads();
  }

  // C/D layout (m74/m101): col = lane&31, row = (p&3) + 8*(p>>2) + 4*hi
  const int row0 = blockIdx.y * TM + wm + 4 * hi;
  const int col0 = blockIdx.x * TN + wn;
  float esum[2][16];  // EPI 3 only: per (mt, p) row sums across both nt
#pragma unroll
  for (int mt = 0; mt < 2; ++mt) {
#pragma unroll
    for (int nt = 0; nt < 2; ++nt) {
      const int col = col0 + nt * 32 + l31;
      float bv = 0.f;
      if constexpr (EPI == 1 || EPI == 2) bv = bias[col];
      float zinv = 1.f;
      if constexpr (EPI == 4) zinv = 1.f / Z[(long)bz * 1024 + col];
#pragma unroll
      for (int p = 0; p < 16; ++p) {
        const float v = acc[mt][nt][p];
        const long rr = row0 + mt * 32 + (p & 3) + ((p >> 2) << 3);
        if constexpr (EPI == 1) {
          const int seg = blockIdx.x / 6;  // 0:Q 1:K 2:V (TN=128 divides 768)
          const int cl = col - seg * 768;
          unsigned short* O = (seg == 0) ? Cb : ((seg == 1) ? Ck : Cv);
          O[rr * 768 + cl] = f2b(v + bv);
        } else if constexpr (EPI == 2) {
          Cf[rr * ldc + col] = v + bv;
        } else if constexpr (EPI == 3) {
          const float e = __expf(v * scale);
          if (nt == 0)
            esum[mt][p] = e;
          else
            esum[mt][p] += e;
          unsigned short* C = Cb + (long)bz * bsC;
          C[rr * ldc + col] = f2b(e);
        } else {  // EPI 4
          unsigned short* C = Cb + (long)bz * bsC;
          C[rr * ldc + col] = f2b(v * zinv);
        }
      }
    }
    if constexpr (EPI == 3) {
#pragma unroll
      for (int p = 0; p < 16; ++p) {
        float s = esum[mt][p];
        s += __shfl_xor(s, 1);
        s += __shfl_xor(s, 2);
        s += __shfl_xor(s, 4);
        s += __shfl_xor(s, 8);
        s += __shfl_xor(s, 16);
        if (l31 == 0) {
          const long rr = row0 + mt * 32 + (p & 3) + ((p >> 2) << 3);
          atomicAdd(&Z[(long)bz * 1024 + rr], s);
        }
      }
    }
  }
}

// fp32 -> bf16 elementwise (x), vectorized
__global__ __launch_bounds__(256) void cvt_x(const float4* __restrict__ x,
                                             ushort4* __restrict__ y, long n4) {
  const long i = (long)blockIdx.x * 256 + threadIdx.x;
  if (i < n4) {
    float4 f = x[i];
    ushort4 o;
    o.x = f2b(f.x); o.y = f2b(f.y); o.z = f2b(f.z); o.w = f2b(f.w);
    y[i] = o;
  }
}

// W[RxC] fp32 -> Wt[CxR] bf16 (coalesced writes; small tensors)
__global__ __launch_bounds__(256) void tcvt(const float* __restrict__ W,
                                            unsigned short* __restrict__ Wt,
                                            int R, int C) {
  const long i = (long)blockIdx.x * 256 + threadIdx.x;
  if (i < (long)R * C) {
    const int k = (int)(i % R);
    const int j = (int)(i / R);
    Wt[i] = f2b(W[(long)k * C + j]);
  }
}

// per-batch V[1024][768] -> Vt[768][1024], bf16, 64x64 LDS tiles
__global__ __launch_bounds__(256) void transpose_v(
    const unsigned short* __restrict__ V, unsigned short* __restrict__ Vt) {
  __shared__ unsigned short T[64][72];
  const int b = blockIdx.z;
  const int d0 = blockIdx.x << 6;
  const int m0 = blockIdx.y << 6;
  const unsigned short* Vb = V + (long)b * 786432;
  unsigned short* Vtb = Vt + (long)b * 786432;
  const int tid = threadIdx.x;
  const int r = tid >> 2;
  const int c4 = tid & 3;
#pragma unroll
  for (int h = 0; h < 2; ++h) {
    const int cc = (c4 + (h << 2)) << 3;
    *(uint4*)&T[r][cc] = *(const uint4*)&Vb[(long)(m0 + r) * 768 + d0 + cc];
  }
  __syncthreads();
#pragma unroll
  for (int h = 0; h < 2; ++h) {
    const int mm = (c4 + (h << 2)) << 3;
    alignas(16) unsigned short tmp[8];
#pragma unroll
    for (int e = 0; e < 8; ++e) tmp[e] = T[mm + e][r];
    *(uint4*)&Vtb[(long)(d0 + r) * 1024 + m0 + mm] = *(uint4*)tmp;
  }
}

extern "C" void kernel_launch(void* const* d_in, const int* in_sizes, int n_in,
                              void* d_out, int out_size, void* d_ws,
                              size_t ws_size, hipStream_t stream) {
  const float* x = (const float*)d_in[0];
  const float* qkv_w = (const float*)d_in[1];
  const float* qkv_b = (const float*)d_in[2];
  const float* proj_w = (const float*)d_in[3];
  const float* proj_b = (const float*)d_in[4];
  float* out = (float*)d_out;

  char* ws = (char*)d_ws;
  unsigned short* x_bf = (unsigned short*)ws;
  unsigned short* Wqkv = (unsigned short*)(ws + 50331648);
  unsigned short* Wp = (unsigned short*)(ws + 53870592);
  unsigned short* Qb = (unsigned short*)(ws + 55050240);
  unsigned short* Kb = (unsigned short*)(ws + 105381888);
  unsigned short* Vb = (unsigned short*)(ws + 155713536);
  unsigned short* Sb = (unsigned short*)(ws + 206045184);
  unsigned short* Vt = x_bf;  // x_bf dead after G1
  unsigned short* Hb = Qb;    // Q dead after G2
  float* Zs = (float*)Vb;     // V dead after transpose_v

  // 1) convert inputs to bf16 (weights also transposed to [n][k])
  cvt_x<<<24576, 256, 0, stream>>>((const float4*)x, (ushort4*)x_bf, 6291456);
  tcvt<<<(1769472 + 255) / 256, 256, 0, stream>>>(qkv_w, Wqkv, 768, 2304);
  tcvt<<<(589824 + 255) / 256, 256, 0, stream>>>(proj_w, Wp, 768, 768);

  // 2) QKV GEMM: [32768x768] x [2304x768]^T + bias -> Q,K,V bf16
  gemm_nt<1><<<dim3(18, 256, 1), 256, 0, stream>>>(
      x_bf, Wqkv, Qb, Kb, Vb, nullptr, qkv_b, nullptr, 768, 768, 768, 0, 0, 0,
      0, 1.f);

  // 3) V -> V^T per batch
  transpose_v<<<dim3(12, 16, 32), 256, 0, stream>>>(Vb, Vt);

  // 3b) zero the softmax row-sum accumulator (V region is now dead)
  hipMemsetAsync(Zs, 0, 32 * 1024 * sizeof(float), stream);

  // 4) E[b] = exp(Q[b] K[b]^T / sqrt(768)) bf16 + row sums into Zs
  gemm_nt<3><<<dim3(8, 8, 32), 256, 0, stream>>>(
      Qb, Kb, Sb, nullptr, nullptr, nullptr, nullptr, Zs, 768, 768, 768, 1024,
      786432, 786432, 1048576, 0.03608439182435161f);

  // 5) O^T: hbuf[b][d][n] = (sum_m Vt[b][d][m] E[b][n][m]) / Z[b][n]
  gemm_nt<4><<<dim3(8, 6, 32), 256, 0, stream>>>(
      Vt, Sb, Hb, nullptr, nullptr, nullptr, nullptr, Zs, 1024, 1024, 1024,
      1024, 786432, 1048576, 786432, 1.f);

  // 6) proj: out[32768x768] = hbuf x Wp^T + bias, fp32
  gemm_nt<2><<<dim3(6, 256, 1), 256, 0, stream>>>(
      Hb, Wp, nullptr, nullptr, nullptr, out, proj_b, nullptr, 768, 768, 768,
      768, 0, 0, 0, 1.f);
}

// Round 6
// 586.939 us; speedup vs baseline: 1.4152x; 1.0448x over previous
//
#include <hip/hip_runtime.h>
#include <hip/hip_bf16.h>

// ---------------------------------------------------------------------------
// BlipAttention: x(32,1024,768) -> qkv -> attention -> scramble -> proj
// All-bf16 MFMA pipeline, fp32 accumulation.
// R2: softmax fused into G2/G4 epilogues (exp + atomic row sums + 1/Z scale).
// R3: 32x32x16 MFMA (2382 TF ceiling), wave = 64x64 out = 2x2 tiles.
// R4 (reverted): operand-order LDS killed staging coalescing.
// R5: XOR swizzle sigma(r,c)=c^(r&7)^(((r>>3)&3)<<1). NOTE: conflict counter
//     unchanged at 4 cyc/ds_read_b128 across 3 different swizzles (only R2's
//     16x16 pattern hit 0) — model failed twice, stop tuning this.
// R6: XCD-locality grid swap (by-fastest block order) for G1/G5 — cuts the
//     ~5x x-slice over-fetch (262MB -> ~60MB predicted); prep kernels merged
//     into one dispatch.
// ---------------------------------------------------------------------------

#define TM 128
#define TN 128
#define BK 64

typedef __attribute__((ext_vector_type(8))) short bf16x8;
typedef __attribute__((ext_vector_type(16))) float f32x16;

__device__ __forceinline__ unsigned short f2b(float f) {
  unsigned int u = __float_as_uint(f);
  u = u + 0x7fffu + ((u >> 16) & 1u);
  return (unsigned short)(u >> 16);
}

__device__ __forceinline__ void g2l16(const void* g, void* l) {
  __builtin_amdgcn_global_load_lds(
      (const __attribute__((address_space(1))) unsigned int*)g,
      (__attribute__((address_space(3))) unsigned int*)l, 16, 0, 0);
}

// NT GEMM: C[m][n] = sum_k A[m][k] * B[n][k]; A,B bf16 row-major (K contig).
// EPI 1: QKV split: bias add, write Q/K/V bf16 (seg = bx/6)
// EPI 2: fp32 out + bias
// EPI 3: E = exp(v*scale) bf16 out + atomic row-sum accumulation into Z
// EPI 4: bf16 out = v * (1/Z[col])
// SWAP: blockIdx.x carries the M-tile (row) index -> consecutive blocks
// (round-robin across XCDs) share the same B column-tile and differ in rows,
// so each XCD touches ~1/8 of the A rows (L2 locality).
template <int EPI, int SWAP>
__global__ __launch_bounds__(256) void gemm_nt(
    const unsigned short* __restrict__ A, const unsigned short* __restrict__ B,
    unsigned short* __restrict__ Cb, unsigned short* __restrict__ Ck,
    unsigned short* __restrict__ Cv, float* __restrict__ Cf,
    const float* __restrict__ bias, float* __restrict__ Z, int K, int lda,
    int ldb, int ldc, long bsA, long bsB, long bsC, float scale) {
  __shared__ unsigned short As[TM * BK];  // 16 KB
  __shared__ unsigned short Bs[TN * BK];  // 16 KB

  const int bx = SWAP ? blockIdx.y : blockIdx.x;
  const int by = SWAP ? blockIdx.x : blockIdx.y;
  const int bz = blockIdx.z;
  const unsigned short* Ag = A + (long)bz * bsA + (long)(by * TM) * lda;
  const unsigned short* Bg = B + (long)bz * bsB + (long)(bx * TN) * ldb;

  const int tid = threadIdx.x;
  const int wave = tid >> 6;
  const int lane = tid & 63;
  const int l31 = lane & 31;
  const int hi = lane >> 5;
  const int wm = (wave & 1) << 6;
  const int wn = (wave >> 1) << 6;

  f32x16 acc[2][2];
#pragma unroll
  for (int mt = 0; mt < 2; ++mt)
#pragma unroll
    for (int nt = 0; nt < 2; ++nt)
#pragma unroll
      for (int p = 0; p < 16; ++p) acc[mt][nt][p] = 0.f;

  // staging: wave covers rows wave*32..+31; 4 issues of 8 rows; lane ->
  // (row = i*8 + lane>>3, LDS slot sj = lane&7, global chunk sj ^ g(r)).
  const int sj = lane & 7;
  const int srow = lane >> 3;

  int ga[2], gb[2];
#pragma unroll
  for (int t = 0; t < 2; ++t) {
    const int ra = wm + t * 32 + l31;
    const int rb = wn + t * 32 + l31;
    ga[t] = (ra & 7) ^ (((ra >> 3) & 3) << 1);
    gb[t] = (rb & 7) ^ (((rb >> 3) & 3) << 1);
  }

  for (int k0 = 0; k0 < K; k0 += BK) {
#pragma unroll
    for (int i = 0; i < 4; ++i) {
      const int r = (wave << 5) + (i << 3) + srow;
      const int g = srow ^ ((i & 3) << 1);  // (r&7) ^ (((r>>3)&3)<<1)
      const int cg = (sj ^ g) << 3;
      g2l16(Ag + (long)r * lda + (k0 + cg), &As[(wave << 11) + (i << 9)]);
      g2l16(Bg + (long)r * ldb + (k0 + cg), &Bs[(wave << 11) + (i << 9)]);
    }
    __syncthreads();
#pragma unroll
    for (int s = 0; s < 4; ++s) {
      const int c = (s << 1) | hi;
      bf16x8 af[2], bfr[2];
#pragma unroll
      for (int t = 0; t < 2; ++t) {
        const int ra = wm + t * 32 + l31;
        const int rb = wn + t * 32 + l31;
        af[t] = *(const bf16x8*)&As[(ra << 6) + ((c ^ ga[t]) << 3)];
        bfr[t] = *(const bf16x8*)&Bs[(rb << 6) + ((c ^ gb[t]) << 3)];
      }
#pragma unroll
      for (int mt = 0; mt < 2; ++mt)
#pragma unroll
        for (int nt = 0; nt < 2; ++nt)
          acc[mt][nt] = __builtin_amdgcn_mfma_f32_32x32x16_bf16(
              af[mt], bfr[nt], acc[mt][nt], 0, 0, 0);
    }
    __syncthreads();
  }

  // C/D layout (m74/m101): col = lane&31, row = (p&3) + 8*(p>>2) + 4*hi
  const int row0 = by * TM + wm + 4 * hi;
  const int col0 = bx * TN + wn;
  float esum[2][16];  // EPI 3 only
#pragma unroll
  for (int mt = 0; mt < 2; ++mt) {
#pragma unroll
    for (int nt = 0; nt < 2; ++nt) {
      const int col = col0 + nt * 32 + l31;
      float bv = 0.f;
      if constexpr (EPI == 1 || EPI == 2) bv = bias[col];
      float zinv = 1.f;
      if constexpr (EPI == 4) zinv = 1.f / Z[(long)bz * 1024 + col];
#pragma unroll
      for (int p = 0; p < 16; ++p) {
        const float v = acc[mt][nt][p];
        const long rr = row0 + mt * 32 + (p & 3) + ((p >> 2) << 3);
        if constexpr (EPI == 1) {
          const int seg = bx / 6;  // 0:Q 1:K 2:V (TN=128 divides 768)
          const int cl = col - seg * 768;
          unsigned short* O = (seg == 0) ? Cb : ((seg == 1) ? Ck : Cv);
          O[rr * 768 + cl] = f2b(v + bv);
        } else if constexpr (EPI == 2) {
          Cf[rr * ldc + col] = v + bv;
        } else if constexpr (EPI == 3) {
          const float e = __expf(v * scale);
          if (nt == 0)
            esum[mt][p] = e;
          else
            esum[mt][p] += e;
          unsigned short* C = Cb + (long)bz * bsC;
          C[rr * ldc + col] = f2b(e);
        } else {  // EPI 4
          unsigned short* C = Cb + (long)bz * bsC;
          C[rr * ldc + col] = f2b(v * zinv);
        }
      }
    }
    if constexpr (EPI == 3) {
#pragma unroll
      for (int p = 0; p < 16; ++p) {
        float s = esum[mt][p];
        s += __shfl_xor(s, 1);
        s += __shfl_xor(s, 2);
        s += __shfl_xor(s, 4);
        s += __shfl_xor(s, 8);
        s += __shfl_xor(s, 16);
        if (l31 == 0) {
          const long rr = row0 + mt * 32 + (p & 3) + ((p >> 2) << 3);
          atomicAdd(&Z[(long)bz * 1024 + rr], s);
        }
      }
    }
  }
}

// merged prep: cvt_x (blocks [0,24576)) + tcvt qkv_w (next 6912) +
// tcvt proj_w (next 2304)
__global__ __launch_bounds__(256) void prep(
    const float4* __restrict__ x, ushort4* __restrict__ x_bf,
    const float* __restrict__ qkv_w, unsigned short* __restrict__ Wqkv,
    const float* __restrict__ proj_w, unsigned short* __restrict__ Wp) {
  const int blk = blockIdx.x;
  if (blk < 24576) {
    const long i = (long)blk * 256 + threadIdx.x;
    float4 f = x[i];
    ushort4 o;
    o.x = f2b(f.x); o.y = f2b(f.y); o.z = f2b(f.z); o.w = f2b(f.w);
    x_bf[i] = o;
  } else if (blk < 24576 + 6912) {
    const long i = (long)(blk - 24576) * 256 + threadIdx.x;
    const int k = (int)(i % 768);
    const int j = (int)(i / 768);
    Wqkv[i] = f2b(qkv_w[(long)k * 2304 + j]);
  } else {
    const long i = (long)(blk - 24576 - 6912) * 256 + threadIdx.x;
    const int k = (int)(i % 768);
    const int j = (int)(i / 768);
    Wp[i] = f2b(proj_w[(long)k * 768 + j]);
  }
}

// per-batch V[1024][768] -> Vt[768][1024], bf16, 64x64 LDS tiles
__global__ __launch_bounds__(256) void transpose_v(
    const unsigned short* __restrict__ V, unsigned short* __restrict__ Vt) {
  __shared__ unsigned short T[64][72];
  const int b = blockIdx.z;
  const int d0 = blockIdx.x << 6;
  const int m0 = blockIdx.y << 6;
  const unsigned short* Vb = V + (long)b * 786432;
  unsigned short* Vtb = Vt + (long)b * 786432;
  const int tid = threadIdx.x;
  const int r = tid >> 2;
  const int c4 = tid & 3;
#pragma unroll
  for (int h = 0; h < 2; ++h) {
    const int cc = (c4 + (h << 2)) << 3;
    *(uint4*)&T[r][cc] = *(const uint4*)&Vb[(long)(m0 + r) * 768 + d0 + cc];
  }
  __syncthreads();
#pragma unroll
  for (int h = 0; h < 2; ++h) {
    const int mm = (c4 + (h << 2)) << 3;
    alignas(16) unsigned short tmp[8];
#pragma unroll
    for (int e = 0; e < 8; ++e) tmp[e] = T[mm + e][r];
    *(uint4*)&Vtb[(long)(d0 + r) * 1024 + m0 + mm] = *(uint4*)tmp;
  }
}

extern "C" void kernel_launch(void* const* d_in, const int* in_sizes, int n_in,
                              void* d_out, int out_size, void* d_ws,
                              size_t ws_size, hipStream_t stream) {
  const float* x = (const float*)d_in[0];
  const float* qkv_w = (const float*)d_in[1];
  const float* qkv_b = (const float*)d_in[2];
  const float* proj_w = (const float*)d_in[3];
  const float* proj_b = (const float*)d_in[4];
  float* out = (float*)d_out;

  char* ws = (char*)d_ws;
  unsigned short* x_bf = (unsigned short*)ws;
  unsigned short* Wqkv = (unsigned short*)(ws + 50331648);
  unsigned short* Wp = (unsigned short*)(ws + 53870592);
  unsigned short* Qb = (unsigned short*)(ws + 55050240);
  unsigned short* Kb = (unsigned short*)(ws + 105381888);
  unsigned short* Vb = (unsigned short*)(ws + 155713536);
  unsigned short* Sb = (unsigned short*)(ws + 206045184);
  unsigned short* Vt = x_bf;  // x_bf dead after G1
  unsigned short* Hb = Qb;    // Q dead after G2
  float* Zs = (float*)Vb;     // V dead after transpose_v

  // 1) convert inputs to bf16 (weights transposed), single dispatch
  prep<<<33792, 256, 0, stream>>>((const float4*)x, (ushort4*)x_bf, qkv_w,
                                  Wqkv, proj_w, Wp);

  // 2) QKV GEMM: [32768x768] x [2304x768]^T + bias -> Q,K,V bf16
  //    (by-fastest grid: XCD row locality)
  gemm_nt<1, 1><<<dim3(256, 18, 1), 256, 0, stream>>>(
      x_bf, Wqkv, Qb, Kb, Vb, nullptr, qkv_b, nullptr, 768, 768, 768, 0, 0, 0,
      0, 1.f);

  // 3) V -> V^T per batch
  transpose_v<<<dim3(12, 16, 32), 256, 0, stream>>>(Vb, Vt);

  // 3b) zero the softmax row-sum accumulator (V region is now dead)
  hipMemsetAsync(Zs, 0, 32 * 1024 * sizeof(float), stream);

  // 4) E[b] = exp(Q[b] K[b]^T / sqrt(768)) bf16 + row sums into Zs
  gemm_nt<3, 0><<<dim3(8, 8, 32), 256, 0, stream>>>(
      Qb, Kb, Sb, nullptr, nullptr, nullptr, nullptr, Zs, 768, 768, 768, 1024,
      786432, 786432, 1048576, 0.03608439182435161f);

  // 5) O^T: hbuf[b][d][n] = (sum_m Vt[b][d][m] E[b][n][m]) / Z[b][n]
  gemm_nt<4, 0><<<dim3(8, 6, 32), 256, 0, stream>>>(
      Vt, Sb, Hb, nullptr, nullptr, nullptr, nullptr, Zs, 1024, 1024, 1024,
      1024, 786432, 1048576, 786432, 1.f);

  // 6) proj: out[32768x768] = hbuf x Wp^T + bias, fp32 (by-fastest grid)
  gemm_nt<2, 1><<<dim3(256, 6, 1), 256, 0, stream>>>(
      Hb, Wp, nullptr, nullptr, nullptr, out, proj_b, nullptr, 768, 768, 768,
      768, 0, 0, 0, 1.f);
}